// Round 9
// baseline (456.118 us; speedup 1.0000x reference)
//
#include <hip/hip_runtime.h>
#include <math.h>

typedef unsigned short u16;
typedef unsigned int   u32;
typedef __attribute__((ext_vector_type(8))) short bf16x8;
typedef __attribute__((ext_vector_type(4))) float f32x4;
typedef __attribute__((ext_vector_type(4))) u32   u32x4;

__device__ __forceinline__ float b2f(u16 u) {
  union { u32 i; float f; } v; v.i = ((u32)u) << 16; return v.f;
}
__device__ __forceinline__ u16 f2b(float f) {
  union { u32 i; float f; } v; v.f = f;
  u32 r = v.i + 0x7FFFu + ((v.i >> 16) & 1u);
  return (u16)(r >> 16);
}
__device__ __forceinline__ float blo(u32 w) {
  union { u32 i; float f; } v; v.i = w << 16; return v.f;
}
__device__ __forceinline__ float bhi(u32 w) {
  union { u32 i; float f; } v; v.i = w & 0xFFFF0000u; return v.f;
}
// async global->LDS, 16B per lane; dest is wave-uniform base + lane*16
__device__ __forceinline__ void ld_lds16(const u16* g, u16* l) {
  __builtin_amdgcn_global_load_lds((const __attribute__((address_space(1))) void*)g,
                                   (__attribute__((address_space(3))) void*)l, 16, 0, 0);
}

#define NN 50000
#define NE 400000
#define NT 450000   // NE + NN self loops
#define NBLK_SCAN 196  // ceil(50000/256)

// ---------------- dtype detection ----------------
__global__ void k_detect(const void* x, const void* ei, int* flags) {
  __shared__ int cnt[2];
  int t = threadIdx.x; // 128 threads
  if (t < 2) cnt[t] = 0;
  __syncthreads();
  u16 u = ((const u16*)x)[t];
  int e = (u >> 7) & 0xFF;
  if (u == 0 || (e >= 90 && e <= 134)) atomicAdd(&cnt[0], 1);
  if (t < 16) {
    if (((const int*)ei)[2 * t + 1] == 0) atomicAdd(&cnt[1], 1);
  }
  __syncthreads();
  if (t == 0) {
    flags[0] = (cnt[0] >= 110) ? 1 : 0;
    flags[1] = (cnt[1] >= 15) ? 1 : 0;
  }
}

__device__ __forceinline__ int eidx(const int* ei, int pos, int i64) {
  return i64 ? ei[2 * pos] : ei[pos];
}

// ---------------- conversions / packing ----------------
__global__ void k_convert_x(const void* x, const int* flags, u16* xb) {
  if (flags[0]) return;
  int c = blockIdx.x * 256 + threadIdx.x;  // chunk of 8 elems
  const float* xf = (const float*)x + (size_t)c * 8;
  u32x4 o;
  #pragma unroll
  for (int i = 0; i < 4; ++i) {
    u32 lo = f2b(xf[2 * i]);
    u32 hi = f2b(xf[2 * i + 1]);
    o[i] = lo | (hi << 16);
  }
  *(u32x4*)(xb + (size_t)c * 8) = o;
}

// merged packing: blocks [0,2048) -> w1t (1024 rows x 512, transposed Wl1|Wr1),
// [2048,2240) -> w23t, [2240,2245) -> params.
__global__ void k_pack(const void* Wl1, const void* Wr1, const void* Wl2, const void* Wr2,
                       const void* Wl3, const void* Wr3, const void* att1, const void* b1,
                       const void* att2, const void* b2, const void* att3, const void* b3,
                       const int* flags, u16* w1t, u16* w23t, float* params) {
  int b = blockIdx.x;
  int isbf = flags[0];
  if (b < 2048) {
    int t = b * 256 + threadIdx.x;
    int r = t >> 9;          // B-row 0..1023
    int k = t & 511;
    const void* W = (r < 512) ? Wl1 : Wr1;
    int cc = r & 511;
    u16 v = isbf ? ((const u16*)W)[k * 512 + cc] : f2b(((const float*)W)[k * 512 + cc]);
    w1t[(size_t)r * 512 + k] = v;
  } else if (b < 2240) {
    int t = (b - 2048) * 256 + threadIdx.x;
    int k = t / 96;
    int c = t % 96;
    const void* W = nullptr; int idx = 0;
    if (c < 40)      { W = Wl2; idx = k * 40 + c; }
    else if (c < 42) { W = Wl3; idx = k * 2 + (c - 40); }
    else if (c < 82) { W = Wr2; idx = k * 40 + (c - 42); }
    else if (c < 84) { W = Wr3; idx = k * 2 + (c - 82); }
    u16 v = 0;
    if (W) v = isbf ? ((const u16*)W)[idx] : f2b(((const float*)W)[idx]);
    w23t[c * 512 + k] = v;
  } else {
    int t = (b - 2240) * 256 + threadIdx.x;
    if (t >= 1108) return;
    const void* src; int idx;
    if (t < 512)       { src = att1; idx = t; }
    else if (t < 1024) { src = b1;   idx = t - 512; }
    else if (t < 1064) { src = att2; idx = t - 1024; }
    else if (t < 1104) { src = b2;   idx = t - 1064; }
    else if (t < 1106) { src = att3; idx = t - 1104; }
    else               { src = b3;   idx = t - 1106; }
    params[t] = isbf ? b2f(((const u16*)src)[idx]) : ((const float*)src)[idx];
  }
}

// ---------------- CSR build ----------------
__global__ void k_hist(const int* ei, const int* flags, int* deg) {
  int e = blockIdx.x * 256 + threadIdx.x;
  if (e >= NE) return;
  int d = eidx(ei, NE + e, flags[1]);
  atomicAdd(&deg[d], 1);
}

__global__ void k_scanA(const int* deg, int* row_ptr, int* bsum) {
  __shared__ int sh[256];
  int b = blockIdx.x, t = threadIdx.x;
  int i = b * 256 + t;
  int val = (i < NN) ? deg[i] + 1 : 0;
  sh[t] = val;
  __syncthreads();
  #pragma unroll
  for (int off = 1; off < 256; off <<= 1) {
    int v = (t >= off) ? sh[t - off] : 0;
    __syncthreads();
    sh[t] += v;
    __syncthreads();
  }
  if (i < NN) row_ptr[i] = sh[t] - val;
  if (t == 255) bsum[b] = sh[255];
}

__global__ void k_scanB(int* bsum, int* row_ptr) {
  __shared__ int sh[256];
  int t = threadIdx.x;
  int val = (t < NBLK_SCAN) ? bsum[t] : 0;
  sh[t] = val;
  __syncthreads();
  #pragma unroll
  for (int off = 1; off < 256; off <<= 1) {
    int v = (t >= off) ? sh[t - off] : 0;
    __syncthreads();
    sh[t] += v;
    __syncthreads();
  }
  if (t < NBLK_SCAN) bsum[t] = sh[t] - val;
  if (t == 255) row_ptr[NN] = sh[255];
}

__global__ void k_scanC(const int* bsum, int* row_ptr, int* cursor) {
  int i = blockIdx.x * 256 + threadIdx.x;
  if (i < NN) {
    int v = row_ptr[i] + bsum[blockIdx.x];
    row_ptr[i] = v;
    cursor[i] = v;
  }
}

__global__ void k_scatter(const int* ei, const int* flags, int* cursor, int* csr_src) {
  int t = blockIdx.x * 256 + threadIdx.x;
  if (t >= NT) return;
  int i64 = flags[1];
  int s, d;
  if (t < NE) { s = eidx(ei, t, i64); d = eidx(ei, NE + t, i64); }
  else        { s = d = t - NE; }
  int pos = atomicAdd(&cursor[d], 1);
  csr_src[pos] = s;
}

// ---------------- GEMM1: xl1/xr1[50000,512] = A @ w1t^T ----------------
// BK=64, A+B staged in LDS via global_load_lds, XOR chunk swizzle (source-side,
// keeps LDS dest lane-contiguous) -> fragment ds_read_b128 2-way banks (free).
// XCD-aware mapping: XCD x owns m-tiles x*49.., all 8 n-tiles back-to-back.
// NOTE (R6 lesson): B direct-from-global per K-step is a 16-line gather on the
// MFMA critical path -> 145us. LDS-staged B (this version) measures 82.5us.
__global__ __launch_bounds__(256) void k_gemm1(const void* __restrict__ xraw, const u16* __restrict__ xb,
                                               const u16* __restrict__ Bt, const int* __restrict__ flags,
                                               u16* __restrict__ XL, u16* __restrict__ XR) {
  __shared__ __align__(16) u16 As[128 * 64];
  __shared__ __align__(16) u16 Bs[128 * 64];
  const int id  = blockIdx.x;
  const int xcd = id & 7;
  const int lb  = id >> 3;
  const int mt  = xcd * 49 + (lb >> 3);
  const int nt  = lb & 7;
  if (mt >= 391) return;
  const int m0 = mt * 128;
  const int n0 = nt * 128;
  const u16* __restrict__ A = flags[0] ? (const u16*)xraw : xb;
  const int t = threadIdx.x;
  const int wave = t >> 6;
  const int lane = t & 63;
  const int wm = (wave >> 1) * 64;
  const int wn = (wave & 1) * 64;
  const int fr = lane & 15;
  const int fk = lane >> 4;
  const int srow = lane >> 3;               // 0..7: row within 8-row staging group
  const int schk = (lane & 7) ^ srow;       // XOR-swizzled source chunk (16B units)
  f32x4 acc[4][4] = {};
  for (int k0 = 0; k0 < 512; k0 += 64) {
    #pragma unroll
    for (int q = 0; q < 4; ++q) {
      int rbase = wave * 32 + q * 8;        // wave stages rows [wave*32, wave*32+32)
      int gm = m0 + rbase + srow;
      if (gm > NN - 1) gm = NN - 1;         // clamp: never read past input x
      ld_lds16(&A[(size_t)gm * 512 + k0 + schk * 8], &As[rbase * 64]);
      ld_lds16(&Bt[(size_t)(n0 + rbase + srow) * 512 + k0 + schk * 8], &Bs[rbase * 64]);
    }
    __syncthreads();
    #pragma unroll
    for (int h = 0; h < 2; ++h) {
      int s = h * 4 + fk;                   // k-chunk select 0..7
      bf16x8 af[4], bb[4];
      #pragma unroll
      for (int i = 0; i < 4; ++i) {
        int row = wm + i * 16 + fr;
        af[i] = *(const bf16x8*)&As[row * 64 + ((s ^ (row & 7)) * 8)];
      }
      #pragma unroll
      for (int j = 0; j < 4; ++j) {
        int row = wn + j * 16 + fr;
        bb[j] = *(const bf16x8*)&Bs[row * 64 + ((s ^ (row & 7)) * 8)];
      }
      #pragma unroll
      for (int i = 0; i < 4; ++i)
        #pragma unroll
        for (int j = 0; j < 4; ++j)
          acc[i][j] = __builtin_amdgcn_mfma_f32_16x16x32_bf16(af[i], bb[j], acc[i][j], 0, 0, 0);
    }
    __syncthreads();
  }
  #pragma unroll
  for (int i = 0; i < 4; ++i) {
    #pragma unroll
    for (int r = 0; r < 4; ++r) {
      int gm = m0 + wm + i * 16 + fk * 4 + r;  // C/D: row=(lane>>4)*4+reg, col=lane&15
      if (gm < NN) {
        #pragma unroll
        for (int j = 0; j < 4; ++j) {
          int gn = n0 + wn + j * 16 + fr;
          u16 v = f2b(acc[i][j][r]);
          if (gn < 512) XL[(size_t)gm * 512 + gn] = v;
          else          XR[(size_t)gm * 512 + gn - 512] = v;
        }
      }
    }
  }
}

// ---------------- GEMM2: xlp/xrp[50000,48] = hb @ w23t^T, 128-row tiles ----------------
// R7-proven LDS-staged version. Split + aligned outputs: xlp = channels 0..41,
// xrp = channels 42..83, 48-f32 rows (192B = 3 cache lines exactly).
__global__ __launch_bounds__(256) void k_gemm2(const u16* __restrict__ A, const u16* __restrict__ Bt,
                                               float* __restrict__ xlp, float* __restrict__ xrp) {
  __shared__ __align__(16) short As[128][40];
  __shared__ __align__(16) short Bs[96][40];
  const int m0 = blockIdx.x * 128;
  const int t = threadIdx.x;
  const int wave = t >> 6;
  const int lane = t & 63;
  const int fr = lane & 15;
  const int fk = lane >> 4;
  const int wm = wave * 32;
  f32x4 acc[2][6] = {};
  for (int k0 = 0; k0 < 512; k0 += 32) {
    #pragma unroll
    for (int h = 0; h < 2; ++h) {
      int c = t + h * 256;
      int row = c >> 2, kc = (c & 3) * 8;
      int gm = m0 + row;
      u32x4 va = {0, 0, 0, 0};
      if (gm < NN) va = *(const u32x4*)&A[(size_t)gm * 512 + k0 + kc];
      *(u32x4*)&As[row][kc] = va;
    }
    for (int c = t; c < 384; c += 256) {
      int row = c >> 2, kc = (c & 3) * 8;
      *(u32x4*)&Bs[row][kc] = *(const u32x4*)&Bt[row * 512 + k0 + kc];
    }
    __syncthreads();
    bf16x8 af[2], bb[6];
    #pragma unroll
    for (int i = 0; i < 2; ++i) af[i] = *(const bf16x8*)&As[wm + i * 16 + fr][fk * 8];
    #pragma unroll
    for (int j = 0; j < 6; ++j) bb[j] = *(const bf16x8*)&Bs[j * 16 + fr][fk * 8];
    #pragma unroll
    for (int i = 0; i < 2; ++i)
      #pragma unroll
      for (int j = 0; j < 6; ++j)
        acc[i][j] = __builtin_amdgcn_mfma_f32_16x16x32_bf16(af[i], bb[j], acc[i][j], 0, 0, 0);
    __syncthreads();
  }
  #pragma unroll
  for (int i = 0; i < 2; ++i) {
    #pragma unroll
    for (int j = 0; j < 6; ++j) {
      int gn = j * 16 + fr;
      if (gn < 84) {
        #pragma unroll
        for (int r = 0; r < 4; ++r) {
          int gm = m0 + wm + i * 16 + fk * 4 + r;
          if (gm < NN) {
            if (gn < 42) xlp[(size_t)gm * 48 + gn] = acc[i][j][r];
            else         xrp[(size_t)gm * 48 + gn - 42] = acc[i][j][r];
          }
        }
      }
    }
  }
}

// ---------------- Layer 1 fused: one wave per node, depth-2 x width-4 pipeline ----
// lrelu decomposition, fully in-register:
//   logit = sum_c 0.4*att_c*(|xl+xr| + 1.5*xl) + dR_i,  dR_i = sum_c 0.4*att_c*1.5*xr
// T14 async-split: iteration p+1's four xl1 gathers are issued BEFORE processing
// iteration p (8 loads in flight; each covered by a full ~450cy VALU phase).
// Index prefetch runs 2 iterations ahead. Width stays 4 (masked-slot waste 25%).
__global__ __launch_bounds__(256) void k_layer1f(const u16* __restrict__ xl1, const u16* __restrict__ xr1,
                                                 const int* __restrict__ row_ptr, const int* __restrict__ csr_src,
                                                 const float* __restrict__ params, u16* __restrict__ hb) {
  int wid = blockIdx.x * 4 + (threadIdx.x >> 6);
  int lane = threadIdx.x & 63;
  int nw = gridDim.x * 4;
  float att4[8];
  #pragma unroll
  for (int k = 0; k < 8; ++k) att4[k] = 0.4f * params[lane * 8 + k];
  for (int i = wid; i < NN; i += nw) {
    int e0 = row_ptr[i], e1 = row_ptr[i + 1];
    int last = e1 - 1;
    u32x4 xrv = *(const u32x4*)&xr1[(size_t)i * 512 + lane * 8];
    float xr[8];
    #pragma unroll
    for (int q = 0; q < 4; ++q) { xr[2 * q] = blo(xrv[q]); xr[2 * q + 1] = bhi(xrv[q]); }
    // dR_i: per-node linear term over this head's 64 channels
    float dp = 0.f;
    #pragma unroll
    for (int k = 0; k < 8; ++k) dp = fmaf(att4[k], 1.5f * xr[k], dp);
    dp += __shfl_xor(dp, 1, 64);
    dp += __shfl_xor(dp, 2, 64);
    dp += __shfl_xor(dp, 4, 64);
    float s = 0.f;
    float acc[8] = {0.f, 0.f, 0.f, 0.f, 0.f, 0.f, 0.f, 0.f};
    // pipeline prologue: indices for iter0 + iter1; loads for iter0
    int qa0 = csr_src[e0];
    int qa1 = csr_src[e0 + 1 < e1 ? e0 + 1 : last];
    int qa2 = csr_src[e0 + 2 < e1 ? e0 + 2 : last];
    int qa3 = csr_src[e0 + 3 < e1 ? e0 + 3 : last];
    u32x4 va0 = *(const u32x4*)&xl1[(size_t)qa0 * 512 + lane * 8];
    u32x4 va1 = *(const u32x4*)&xl1[(size_t)qa1 * 512 + lane * 8];
    u32x4 va2 = *(const u32x4*)&xl1[(size_t)qa2 * 512 + lane * 8];
    u32x4 va3 = *(const u32x4*)&xl1[(size_t)qa3 * 512 + lane * 8];
    int qb0 = csr_src[e0 + 4 < e1 ? e0 + 4 : last];
    int qb1 = csr_src[e0 + 5 < e1 ? e0 + 5 : last];
    int qb2 = csr_src[e0 + 6 < e1 ? e0 + 6 : last];
    int qb3 = csr_src[e0 + 7 < e1 ? e0 + 7 : last];
    for (int p = e0; p < e1; p += 4) {
      // issue NEXT iteration's loads first (latency hides under this iteration)
      u32x4 vb0 = *(const u32x4*)&xl1[(size_t)qb0 * 512 + lane * 8];
      u32x4 vb1 = *(const u32x4*)&xl1[(size_t)qb1 * 512 + lane * 8];
      u32x4 vb2 = *(const u32x4*)&xl1[(size_t)qb2 * 512 + lane * 8];
      u32x4 vb3 = *(const u32x4*)&xl1[(size_t)qb3 * 512 + lane * 8];
      // prefetch indices 2 iterations ahead
      int np = p + 8;
      int qc0 = csr_src[np     < e1 ? np     : last];
      int qc1 = csr_src[np + 1 < e1 ? np + 1 : last];
      int qc2 = csr_src[np + 2 < e1 ? np + 2 : last];
      int qc3 = csr_src[np + 3 < e1 ? np + 3 : last];
      // process current quad (va)
      float m1 = (p + 1 < e1) ? 1.f : 0.f;
      float m2 = (p + 2 < e1) ? 1.f : 0.f;
      float m3 = (p + 3 < e1) ? 1.f : 0.f;
      float c0 = 0.f, c1 = 0.f, c2 = 0.f, c3 = 0.f;
      float xlv0[8], xlv1[8], xlv2[8], xlv3[8];
      #pragma unroll
      for (int q = 0; q < 4; ++q) {
        xlv0[2 * q] = blo(va0[q]); xlv0[2 * q + 1] = bhi(va0[q]);
        xlv1[2 * q] = blo(va1[q]); xlv1[2 * q + 1] = bhi(va1[q]);
        xlv2[2 * q] = blo(va2[q]); xlv2[2 * q + 1] = bhi(va2[q]);
        xlv3[2 * q] = blo(va3[q]); xlv3[2 * q + 1] = bhi(va3[q]);
      }
      #pragma unroll
      for (int k = 0; k < 8; ++k) {
        float t0 = xlv0[k] + xr[k];
        float t1 = xlv1[k] + xr[k];
        float t2 = xlv2[k] + xr[k];
        float t3 = xlv3[k] + xr[k];
        float u0 = fmaf(1.5f, xlv0[k], fabsf(t0));
        float u1 = fmaf(1.5f, xlv1[k], fabsf(t1));
        float u2 = fmaf(1.5f, xlv2[k], fabsf(t2));
        float u3 = fmaf(1.5f, xlv3[k], fabsf(t3));
        c0 = fmaf(att4[k], u0, c0);
        c1 = fmaf(att4[k], u1, c1);
        c2 = fmaf(att4[k], u2, c2);
        c3 = fmaf(att4[k], u3, c3);
      }
      c0 += __shfl_xor(c0, 1, 64); c1 += __shfl_xor(c1, 1, 64);
      c2 += __shfl_xor(c2, 1, 64); c3 += __shfl_xor(c3, 1, 64);
      c0 += __shfl_xor(c0, 2, 64); c1 += __shfl_xor(c1, 2, 64);
      c2 += __shfl_xor(c2, 2, 64); c3 += __shfl_xor(c3, 2, 64);
      c0 += __shfl_xor(c0, 4, 64); c1 += __shfl_xor(c1, 4, 64);
      c2 += __shfl_xor(c2, 4, 64); c3 += __shfl_xor(c3, 4, 64);
      float l0 = c0 + dp;
      float l1 = c1 + dp;
      float l2 = c2 + dp;
      float l3 = c3 + dp;
      float pv0 = __expf(fminf(fmaxf(l0, -30.f), 30.f));
      float pv1 = __expf(fminf(fmaxf(l1, -30.f), 30.f)) * m1;
      float pv2 = __expf(fminf(fmaxf(l2, -30.f), 30.f)) * m2;
      float pv3 = __expf(fminf(fmaxf(l3, -30.f), 30.f)) * m3;
      s += (pv0 + pv1) + (pv2 + pv3);
      #pragma unroll
      for (int k = 0; k < 8; ++k) {
        float a = fmaf(pv0, xlv0[k], acc[k]);
        a = fmaf(pv1, xlv1[k], a);
        a = fmaf(pv2, xlv2[k], a);
        acc[k] = fmaf(pv3, xlv3[k], a);
      }
      // rotate pipeline registers
      va0 = vb0; va1 = vb1; va2 = vb2; va3 = vb3;
      qb0 = qc0; qb1 = qc1; qb2 = qc2; qb3 = qc3;
    }
    float r = 1.f / s;
    u32x4 o;
    #pragma unroll
    for (int q = 0; q < 4; ++q) {
      u32 lo = f2b(fmaxf(fmaf(acc[2 * q],     r, params[512 + lane * 8 + 2 * q]),     0.f));
      u32 hi = f2b(fmaxf(fmaf(acc[2 * q + 1], r, params[512 + lane * 8 + 2 * q + 1]), 0.f));
      o[q] = lo | (hi << 16);
    }
    *(u32x4*)&hb[(size_t)i * 512 + lane * 8] = o;
  }
}

// ---------------- Layers 2+3 fused: one wave per node, 8 edge-slots x 8 channel-groups ----
// lane = e*8+g: slot e handles edges e0+e, e0+e+8, ...; group g handles L2 channels
// [5g,5g+5); g==0 additionally handles both L3 channels in-lane (no shfl).
// Logit reduce = 3 shfl per 8 edges; final cross-slot reduce once per node.
// xlp/xrp rows are 192B cacheline-aligned: per-edge gather = exactly 3 lines.
__global__ __launch_bounds__(256) void k_layer23f(const float* __restrict__ xlp, const float* __restrict__ xrp,
                                                  const int* __restrict__ row_ptr, const int* __restrict__ csr_src,
                                                  const float* __restrict__ params,
                                                  const int* __restrict__ flags, void* __restrict__ out) {
  int wid = blockIdx.x * 4 + (threadIdx.x >> 6);
  int lane = threadIdx.x & 63;
  int nw = gridDim.x * 4;
  int e = lane >> 3;   // edge slot 0..7
  int g = lane & 7;    // channel group 0..7
  int c0 = g * 5;      // L2 channels c0..c0+4
  float att2[5];
  #pragma unroll
  for (int u = 0; u < 5; ++u) att2[u] = params[1024 + c0 + u];
  float att3a = params[1104], att3b = params[1105];
  int isbf = flags[0];
  for (int i = wid; i < NN; i += nw) {
    int e0 = row_ptr[i], e1 = row_ptr[i + 1];
    const float* xri = &xrp[(size_t)i * 48];
    float xr2[5];
    #pragma unroll
    for (int u = 0; u < 5; ++u) xr2[u] = xri[c0 + u];
    float xr3a = xri[40], xr3b = xri[41];   // used by g==0 only
    float s2 = 0.f, s3 = 0.f;
    float acc2[5] = {0.f, 0.f, 0.f, 0.f, 0.f};
    float acc3a = 0.f, acc3b = 0.f;
    int nit = (e1 - e0 + 7) >> 3;
    for (int it = 0; it < nit; ++it) {
      int p = e0 + it * 8 + e;
      bool valid = p < e1;
      int j = csr_src[valid ? p : e1 - 1];
      const float* xlj = &xlp[(size_t)j * 48];
      float xl2[5];
      #pragma unroll
      for (int u = 0; u < 5; ++u) xl2[u] = xlj[c0 + u];
      float part = 0.f;
      #pragma unroll
      for (int u = 0; u < 5; ++u) {
        float t = xl2[u] + xr2[u];
        part = fmaf(att2[u], fmaxf(t, 0.2f * t), part);
      }
      part += __shfl_xor(part, 1, 64);
      part += __shfl_xor(part, 2, 64);
      part += __shfl_xor(part, 4, 64);
      float pv2 = valid ? __expf(fminf(fmaxf(part, -30.f), 30.f)) : 0.f;
      s2 += pv2;
      #pragma unroll
      for (int u = 0; u < 5; ++u) acc2[u] = fmaf(pv2, xl2[u], acc2[u]);
      if (g == 0) {   // layer3: 2 channels, fully in-lane
        float xl3a = xlj[40], xl3b = xlj[41];
        float ta = xl3a + xr3a, tb = xl3b + xr3b;
        float l3 = fmaf(att3a, fmaxf(ta, 0.2f * ta), att3b * fmaxf(tb, 0.2f * tb));
        float pv3 = valid ? __expf(fminf(fmaxf(l3, -30.f), 30.f)) : 0.f;
        s3 += pv3;
        acc3a = fmaf(pv3, xl3a, acc3a);
        acc3b = fmaf(pv3, xl3b, acc3b);
      }
    }
    // reduce across the 8 edge slots (lane bits 3..5)
    #pragma unroll
    for (int m = 8; m <= 32; m <<= 1) {
      #pragma unroll
      for (int u = 0; u < 5; ++u) acc2[u] += __shfl_xor(acc2[u], m, 64);
      s2 += __shfl_xor(s2, m, 64);
      acc3a += __shfl_xor(acc3a, m, 64);
      acc3b += __shfl_xor(acc3b, m, 64);
      s3 += __shfl_xor(s3, m, 64);
    }
    if (e == 0) {
      float r2 = 1.f / s2;
      #pragma unroll
      for (int u = 0; u < 5; ++u) {
        float v = acc2[u] * r2 + params[1064 + c0 + u];
        size_t o = (size_t)i * 40 + c0 + u;
        if (isbf) ((u16*)out)[o] = f2b(v); else ((float*)out)[o] = v;
      }
      if (g == 0) {
        float r3 = 1.f / s3;
        float va = acc3a * r3 + params[1106];
        float vb = acc3b * r3 + params[1107];
        size_t o = 2000000 + (size_t)i * 2;
        if (isbf) { ((u16*)out)[o] = f2b(va); ((u16*)out)[o + 1] = f2b(vb); }
        else      { ((float*)out)[o] = va;    ((float*)out)[o + 1] = vb; }
      }
    }
  }
}

extern "C" void kernel_launch(void* const* d_in, const int* in_sizes, int n_in,
                              void* d_out, int out_size, void* d_ws, size_t ws_size,
                              hipStream_t stream) {
  const void* x    = d_in[0];
  const int*  ei   = (const int*)d_in[1];
  const void* Wl1  = d_in[2];
  const void* Wr1  = d_in[3];
  const void* att1 = d_in[4];
  const void* b1   = d_in[5];
  const void* Wl2  = d_in[6];
  const void* Wr2  = d_in[7];
  const void* att2 = d_in[8];
  const void* b2   = d_in[9];
  const void* Wl3  = d_in[10];
  const void* Wr3  = d_in[11];
  const void* att3 = d_in[12];
  const void* b3   = d_in[13];
  (void)in_sizes; (void)n_in; (void)out_size;

  char* ws = (char*)d_ws;
  size_t off = 0;
  auto alloc = [&](size_t bytes) -> void* {
    void* p = ws + off;
    off = (off + bytes + 255) & ~(size_t)255;
    return p;
  };
  int*   flags   = (int*)  alloc(64);
  u16*   xb      = (u16*)  alloc((size_t)NN * 512 * 2);    // 51.2 MB (f32 fallback path)
  u16*   w1t     = (u16*)  alloc((size_t)1024 * 512 * 2);  // 1 MB
  u16*   xl1     = (u16*)  alloc((size_t)NN * 512 * 2);    // 51.2 MB
  u16*   xr1     = (u16*)  alloc((size_t)NN * 512 * 2);    // 51.2 MB
  u16*   hb      = (u16*)  alloc((size_t)NN * 512 * 2);    // 51.2 MB
  u16*   w23t    = (u16*)  alloc((size_t)96 * 512 * 2);
  float* xlp     = (float*)alloc((size_t)NN * 48 * 4);     // 9.6 MB (xl2|xl3, 192B rows)
  float* xrp     = (float*)alloc((size_t)NN * 48 * 4);     // 9.6 MB (xr2|xr3)
  float* params  = (float*)alloc(1108 * 4);
  int*   row_ptr = (int*)  alloc((NN + 1) * 4);
  int*   deg     = (int*)  alloc(NN * 4);
  int*   cursor  = (int*)  alloc(NN * 4);
  int*   csr_src = (int*)  alloc((NT + 16) * 4);
  int*   bsum    = (int*)  alloc(256 * 4);
  if (ws_size < off) return;  // ~228 MB needed

  hipLaunchKernelGGL(k_detect, dim3(1), dim3(128), 0, stream, x, (const void*)ei, flags);
  hipLaunchKernelGGL(k_convert_x, dim3(12500), dim3(256), 0, stream, x, flags, xb);
  hipLaunchKernelGGL(k_pack, dim3(2245), dim3(256), 0, stream, Wl1, Wr1, Wl2, Wr2, Wl3, Wr3,
                     att1, b1, att2, b2, att3, b3, flags, w1t, w23t, params);
  hipMemsetAsync(deg, 0, NN * 4, stream);
  hipLaunchKernelGGL(k_hist, dim3((NE + 255) / 256), dim3(256), 0, stream, ei, flags, deg);
  hipLaunchKernelGGL(k_scanA, dim3(NBLK_SCAN), dim3(256), 0, stream, deg, row_ptr, bsum);
  hipLaunchKernelGGL(k_scanB, dim3(1), dim3(256), 0, stream, bsum, row_ptr);
  hipLaunchKernelGGL(k_scanC, dim3(NBLK_SCAN), dim3(256), 0, stream, bsum, row_ptr, cursor);
  hipLaunchKernelGGL(k_scatter, dim3((NT + 255) / 256), dim3(256), 0, stream, ei, flags, cursor, csr_src);
  hipLaunchKernelGGL(k_gemm1, dim3(3136), dim3(256), 0, stream, x, xb, w1t, flags, xl1, xr1);
  hipLaunchKernelGGL(k_layer1f, dim3(4096), dim3(256), 0, stream, xl1, xr1, row_ptr, csr_src, params, hb);
  hipLaunchKernelGGL(k_gemm2, dim3(391), dim3(256), 0, stream, hb, w23t, xlp, xrp);
  hipLaunchKernelGGL(k_layer23f, dim3(4096), dim3(256), 0, stream, xlp, xrp, row_ptr, csr_src, params, flags, d_out);
}

// Round 10
// 452.514 us; speedup vs baseline: 1.0080x; 1.0080x over previous
//
#include <hip/hip_runtime.h>
#include <math.h>

typedef unsigned short u16;
typedef unsigned int   u32;
typedef __attribute__((ext_vector_type(8))) short bf16x8;
typedef __attribute__((ext_vector_type(4))) float f32x4;
typedef __attribute__((ext_vector_type(2))) float f32x2;
typedef __attribute__((ext_vector_type(4))) u32   u32x4;

__device__ __forceinline__ float b2f(u16 u) {
  union { u32 i; float f; } v; v.i = ((u32)u) << 16; return v.f;
}
__device__ __forceinline__ u16 f2b(float f) {
  union { u32 i; float f; } v; v.f = f;
  u32 r = v.i + 0x7FFFu + ((v.i >> 16) & 1u);
  return (u16)(r >> 16);
}
__device__ __forceinline__ float blo(u32 w) {
  union { u32 i; float f; } v; v.i = w << 16; return v.f;
}
__device__ __forceinline__ float bhi(u32 w) {
  union { u32 i; float f; } v; v.i = w & 0xFFFF0000u; return v.f;
}
// unpack one u32 of 2 packed bf16 into a float2 {lo, hi}
__device__ __forceinline__ f32x2 b2f2(u32 w) {
  f32x2 r; r[0] = blo(w); r[1] = bhi(w); return r;
}
// async global->LDS, 16B per lane; dest is wave-uniform base + lane*16
__device__ __forceinline__ void ld_lds16(const u16* g, u16* l) {
  __builtin_amdgcn_global_load_lds((const __attribute__((address_space(1))) void*)g,
                                   (__attribute__((address_space(3))) void*)l, 16, 0, 0);
}

#define NN 50000
#define NE 400000
#define NT 450000   // NE + NN self loops
#define NBLK_SCAN 196  // ceil(50000/256)

// ---------------- dtype detection ----------------
__global__ void k_detect(const void* x, const void* ei, int* flags) {
  __shared__ int cnt[2];
  int t = threadIdx.x; // 128 threads
  if (t < 2) cnt[t] = 0;
  __syncthreads();
  u16 u = ((const u16*)x)[t];
  int e = (u >> 7) & 0xFF;
  if (u == 0 || (e >= 90 && e <= 134)) atomicAdd(&cnt[0], 1);
  if (t < 16) {
    if (((const int*)ei)[2 * t + 1] == 0) atomicAdd(&cnt[1], 1);
  }
  __syncthreads();
  if (t == 0) {
    flags[0] = (cnt[0] >= 110) ? 1 : 0;
    flags[1] = (cnt[1] >= 15) ? 1 : 0;
  }
}

__device__ __forceinline__ int eidx(const int* ei, int pos, int i64) {
  return i64 ? ei[2 * pos] : ei[pos];
}

// ---------------- conversions / packing ----------------
__global__ void k_convert_x(const void* x, const int* flags, u16* xb) {
  if (flags[0]) return;
  int c = blockIdx.x * 256 + threadIdx.x;  // chunk of 8 elems
  const float* xf = (const float*)x + (size_t)c * 8;
  u32x4 o;
  #pragma unroll
  for (int i = 0; i < 4; ++i) {
    u32 lo = f2b(xf[2 * i]);
    u32 hi = f2b(xf[2 * i + 1]);
    o[i] = lo | (hi << 16);
  }
  *(u32x4*)(xb + (size_t)c * 8) = o;
}

// merged packing: blocks [0,2048) -> w1t (1024 rows x 512, transposed Wl1|Wr1),
// [2048,2240) -> w23t, [2240,2245) -> params.
__global__ void k_pack(const void* Wl1, const void* Wr1, const void* Wl2, const void* Wr2,
                       const void* Wl3, const void* Wr3, const void* att1, const void* b1,
                       const void* att2, const void* b2, const void* att3, const void* b3,
                       const int* flags, u16* w1t, u16* w23t, float* params) {
  int b = blockIdx.x;
  int isbf = flags[0];
  if (b < 2048) {
    int t = b * 256 + threadIdx.x;
    int r = t >> 9;          // B-row 0..1023
    int k = t & 511;
    const void* W = (r < 512) ? Wl1 : Wr1;
    int cc = r & 511;
    u16 v = isbf ? ((const u16*)W)[k * 512 + cc] : f2b(((const float*)W)[k * 512 + cc]);
    w1t[(size_t)r * 512 + k] = v;
  } else if (b < 2240) {
    int t = (b - 2048) * 256 + threadIdx.x;
    int k = t / 96;
    int c = t % 96;
    const void* W = nullptr; int idx = 0;
    if (c < 40)      { W = Wl2; idx = k * 40 + c; }
    else if (c < 42) { W = Wl3; idx = k * 2 + (c - 40); }
    else if (c < 82) { W = Wr2; idx = k * 40 + (c - 42); }
    else if (c < 84) { W = Wr3; idx = k * 2 + (c - 82); }
    u16 v = 0;
    if (W) v = isbf ? ((const u16*)W)[idx] : f2b(((const float*)W)[idx]);
    w23t[c * 512 + k] = v;
  } else {
    int t = (b - 2240) * 256 + threadIdx.x;
    if (t >= 1108) return;
    const void* src; int idx;
    if (t < 512)       { src = att1; idx = t; }
    else if (t < 1024) { src = b1;   idx = t - 512; }
    else if (t < 1064) { src = att2; idx = t - 1024; }
    else if (t < 1104) { src = b2;   idx = t - 1064; }
    else if (t < 1106) { src = att3; idx = t - 1104; }
    else               { src = b3;   idx = t - 1106; }
    params[t] = isbf ? b2f(((const u16*)src)[idx]) : ((const float*)src)[idx];
  }
}

// ---------------- CSR build ----------------
__global__ void k_hist(const int* ei, const int* flags, int* deg) {
  int e = blockIdx.x * 256 + threadIdx.x;
  if (e >= NE) return;
  int d = eidx(ei, NE + e, flags[1]);
  atomicAdd(&deg[d], 1);
}

__global__ void k_scanA(const int* deg, int* row_ptr, int* bsum) {
  __shared__ int sh[256];
  int b = blockIdx.x, t = threadIdx.x;
  int i = b * 256 + t;
  int val = (i < NN) ? deg[i] + 1 : 0;
  sh[t] = val;
  __syncthreads();
  #pragma unroll
  for (int off = 1; off < 256; off <<= 1) {
    int v = (t >= off) ? sh[t - off] : 0;
    __syncthreads();
    sh[t] += v;
    __syncthreads();
  }
  if (i < NN) row_ptr[i] = sh[t] - val;
  if (t == 255) bsum[b] = sh[255];
}

__global__ void k_scanB(int* bsum, int* row_ptr) {
  __shared__ int sh[256];
  int t = threadIdx.x;
  int val = (t < NBLK_SCAN) ? bsum[t] : 0;
  sh[t] = val;
  __syncthreads();
  #pragma unroll
  for (int off = 1; off < 256; off <<= 1) {
    int v = (t >= off) ? sh[t - off] : 0;
    __syncthreads();
    sh[t] += v;
    __syncthreads();
  }
  if (t < NBLK_SCAN) bsum[t] = sh[t] - val;
  if (t == 255) row_ptr[NN] = sh[255];
}

__global__ void k_scanC(const int* bsum, int* row_ptr, int* cursor) {
  int i = blockIdx.x * 256 + threadIdx.x;
  if (i < NN) {
    int v = row_ptr[i] + bsum[blockIdx.x];
    row_ptr[i] = v;
    cursor[i] = v;
  }
}

__global__ void k_scatter(const int* ei, const int* flags, int* cursor, int* csr_src) {
  int t = blockIdx.x * 256 + threadIdx.x;
  if (t >= NT) return;
  int i64 = flags[1];
  int s, d;
  if (t < NE) { s = eidx(ei, t, i64); d = eidx(ei, NE + t, i64); }
  else        { s = d = t - NE; }
  int pos = atomicAdd(&cursor[d], 1);
  csr_src[pos] = s;
}

// ---------------- GEMM1: xl1/xr1[50000,512] = A @ w1t^T ----------------
// BK=64, A+B staged in LDS via global_load_lds, XOR chunk swizzle (source-side,
// keeps LDS dest lane-contiguous) -> fragment ds_read_b128 2-way banks (free).
// XCD-aware mapping: XCD x owns m-tiles x*49.., all 8 n-tiles back-to-back.
// NOTE (R6 lesson): B direct-from-global per K-step is a 16-line gather on the
// MFMA critical path -> 145us. LDS-staged B (this version) measures 82.5us.
__global__ __launch_bounds__(256) void k_gemm1(const void* __restrict__ xraw, const u16* __restrict__ xb,
                                               const u16* __restrict__ Bt, const int* __restrict__ flags,
                                               u16* __restrict__ XL, u16* __restrict__ XR) {
  __shared__ __align__(16) u16 As[128 * 64];
  __shared__ __align__(16) u16 Bs[128 * 64];
  const int id  = blockIdx.x;
  const int xcd = id & 7;
  const int lb  = id >> 3;
  const int mt  = xcd * 49 + (lb >> 3);
  const int nt  = lb & 7;
  if (mt >= 391) return;
  const int m0 = mt * 128;
  const int n0 = nt * 128;
  const u16* __restrict__ A = flags[0] ? (const u16*)xraw : xb;
  const int t = threadIdx.x;
  const int wave = t >> 6;
  const int lane = t & 63;
  const int wm = (wave >> 1) * 64;
  const int wn = (wave & 1) * 64;
  const int fr = lane & 15;
  const int fk = lane >> 4;
  const int srow = lane >> 3;               // 0..7: row within 8-row staging group
  const int schk = (lane & 7) ^ srow;       // XOR-swizzled source chunk (16B units)
  f32x4 acc[4][4] = {};
  for (int k0 = 0; k0 < 512; k0 += 64) {
    #pragma unroll
    for (int q = 0; q < 4; ++q) {
      int rbase = wave * 32 + q * 8;        // wave stages rows [wave*32, wave*32+32)
      int gm = m0 + rbase + srow;
      if (gm > NN - 1) gm = NN - 1;         // clamp: never read past input x
      ld_lds16(&A[(size_t)gm * 512 + k0 + schk * 8], &As[rbase * 64]);
      ld_lds16(&Bt[(size_t)(n0 + rbase + srow) * 512 + k0 + schk * 8], &Bs[rbase * 64]);
    }
    __syncthreads();
    #pragma unroll
    for (int h = 0; h < 2; ++h) {
      int s = h * 4 + fk;                   // k-chunk select 0..7
      bf16x8 af[4], bb[4];
      #pragma unroll
      for (int i = 0; i < 4; ++i) {
        int row = wm + i * 16 + fr;
        af[i] = *(const bf16x8*)&As[row * 64 + ((s ^ (row & 7)) * 8)];
      }
      #pragma unroll
      for (int j = 0; j < 4; ++j) {
        int row = wn + j * 16 + fr;
        bb[j] = *(const bf16x8*)&Bs[row * 64 + ((s ^ (row & 7)) * 8)];
      }
      #pragma unroll
      for (int i = 0; i < 4; ++i)
        #pragma unroll
        for (int j = 0; j < 4; ++j)
          acc[i][j] = __builtin_amdgcn_mfma_f32_16x16x32_bf16(af[i], bb[j], acc[i][j], 0, 0, 0);
    }
    __syncthreads();
  }
  #pragma unroll
  for (int i = 0; i < 4; ++i) {
    #pragma unroll
    for (int r = 0; r < 4; ++r) {
      int gm = m0 + wm + i * 16 + fk * 4 + r;  // C/D: row=(lane>>4)*4+reg, col=lane&15
      if (gm < NN) {
        #pragma unroll
        for (int j = 0; j < 4; ++j) {
          int gn = n0 + wn + j * 16 + fr;
          u16 v = f2b(acc[i][j][r]);
          if (gn < 512) XL[(size_t)gm * 512 + gn] = v;
          else          XR[(size_t)gm * 512 + gn - 512] = v;
        }
      }
    }
  }
}

// ---------------- GEMM2: xlp/xrp[50000,48] = hb @ w23t^T, 128-row tiles ----------------
// R7-proven LDS-staged version. Split + aligned outputs: xlp = channels 0..41,
// xrp = channels 42..83, 48-f32 rows (192B = 3 cache lines exactly).
__global__ __launch_bounds__(256) void k_gemm2(const u16* __restrict__ A, const u16* __restrict__ Bt,
                                               float* __restrict__ xlp, float* __restrict__ xrp) {
  __shared__ __align__(16) short As[128][40];
  __shared__ __align__(16) short Bs[96][40];
  const int m0 = blockIdx.x * 128;
  const int t = threadIdx.x;
  const int wave = t >> 6;
  const int lane = t & 63;
  const int fr = lane & 15;
  const int fk = lane >> 4;
  const int wm = wave * 32;
  f32x4 acc[2][6] = {};
  for (int k0 = 0; k0 < 512; k0 += 32) {
    #pragma unroll
    for (int h = 0; h < 2; ++h) {
      int c = t + h * 256;
      int row = c >> 2, kc = (c & 3) * 8;
      int gm = m0 + row;
      u32x4 va = {0, 0, 0, 0};
      if (gm < NN) va = *(const u32x4*)&A[(size_t)gm * 512 + k0 + kc];
      *(u32x4*)&As[row][kc] = va;
    }
    for (int c = t; c < 384; c += 256) {
      int row = c >> 2, kc = (c & 3) * 8;
      *(u32x4*)&Bs[row][kc] = *(const u32x4*)&Bt[row * 512 + k0 + kc];
    }
    __syncthreads();
    bf16x8 af[2], bb[6];
    #pragma unroll
    for (int i = 0; i < 2; ++i) af[i] = *(const bf16x8*)&As[wm + i * 16 + fr][fk * 8];
    #pragma unroll
    for (int j = 0; j < 6; ++j) bb[j] = *(const bf16x8*)&Bs[j * 16 + fr][fk * 8];
    #pragma unroll
    for (int i = 0; i < 2; ++i)
      #pragma unroll
      for (int j = 0; j < 6; ++j)
        acc[i][j] = __builtin_amdgcn_mfma_f32_16x16x32_bf16(af[i], bb[j], acc[i][j], 0, 0, 0);
    __syncthreads();
  }
  #pragma unroll
  for (int i = 0; i < 2; ++i) {
    #pragma unroll
    for (int j = 0; j < 6; ++j) {
      int gn = j * 16 + fr;
      if (gn < 84) {
        #pragma unroll
        for (int r = 0; r < 4; ++r) {
          int gm = m0 + wm + i * 16 + fk * 4 + r;
          if (gm < NN) {
            if (gn < 42) xlp[(size_t)gm * 48 + gn] = acc[i][j][r];
            else         xrp[(size_t)gm * 48 + gn - 42] = acc[i][j][r];
          }
        }
      }
    }
  }
}

// ---------------- Layer 1 fused: one wave per node, 4 edges in flight (R7 structure),
// channel math in PACKED f32 (float2 -> v_pk_add/v_pk_fma on gfx950).
// lrelu decomposition, fully in-register:
//   logit = sum_c 0.4*att_c*(|xl+xr| + 1.5*xl) + dR_i,  dR_i = sum_c 0.4*att_c*1.5*xr
__global__ __launch_bounds__(256) void k_layer1f(const u16* __restrict__ xl1, const u16* __restrict__ xr1,
                                                 const int* __restrict__ row_ptr, const int* __restrict__ csr_src,
                                                 const float* __restrict__ params, u16* __restrict__ hb) {
  int wid = blockIdx.x * 4 + (threadIdx.x >> 6);
  int lane = threadIdx.x & 63;
  int nw = gridDim.x * 4;
  const f32x2 c15 = {1.5f, 1.5f};
  f32x2 att2[4];
  #pragma unroll
  for (int q = 0; q < 4; ++q) {
    att2[q][0] = 0.4f * params[lane * 8 + 2 * q];
    att2[q][1] = 0.4f * params[lane * 8 + 2 * q + 1];
  }
  for (int i = wid; i < NN; i += nw) {
    int e0 = row_ptr[i], e1 = row_ptr[i + 1];
    u32x4 xrv = *(const u32x4*)&xr1[(size_t)i * 512 + lane * 8];
    f32x2 xr2[4];
    #pragma unroll
    for (int q = 0; q < 4; ++q) xr2[q] = b2f2(xrv[q]);
    // dR_i: per-node linear term over this head's 64 channels
    f32x2 dpv = {0.f, 0.f};
    #pragma unroll
    for (int q = 0; q < 4; ++q) dpv = __builtin_elementwise_fma(att2[q], c15 * xr2[q], dpv);
    float dp = dpv[0] + dpv[1];
    dp += __shfl_xor(dp, 1, 64);
    dp += __shfl_xor(dp, 2, 64);
    dp += __shfl_xor(dp, 4, 64);
    float s = 0.f;
    f32x2 accv[4] = {{0.f, 0.f}, {0.f, 0.f}, {0.f, 0.f}, {0.f, 0.f}};
    // index prefetch: indices for iteration p are loaded during iteration p-4
    int q0 = csr_src[e0];
    int q1 = csr_src[e0 + 1 < e1 ? e0 + 1 : e1 - 1];
    int q2 = csr_src[e0 + 2 < e1 ? e0 + 2 : e1 - 1];
    int q3 = csr_src[e0 + 3 < e1 ? e0 + 3 : e1 - 1];
    for (int p = e0; p < e1; p += 4) {
      int j0 = q0, j1 = q1, j2 = q2, j3 = q3;
      u32x4 v0 = *(const u32x4*)&xl1[(size_t)j0 * 512 + lane * 8];
      u32x4 v1 = *(const u32x4*)&xl1[(size_t)j1 * 512 + lane * 8];
      u32x4 v2 = *(const u32x4*)&xl1[(size_t)j2 * 512 + lane * 8];
      u32x4 v3 = *(const u32x4*)&xl1[(size_t)j3 * 512 + lane * 8];
      int np = p + 4;
      if (np < e1) {
        q0 = csr_src[np];
        q1 = csr_src[np + 1 < e1 ? np + 1 : e1 - 1];
        q2 = csr_src[np + 2 < e1 ? np + 2 : e1 - 1];
        q3 = csr_src[np + 3 < e1 ? np + 3 : e1 - 1];
      }
      float m1 = (p + 1 < e1) ? 1.f : 0.f;
      float m2 = (p + 2 < e1) ? 1.f : 0.f;
      float m3 = (p + 3 < e1) ? 1.f : 0.f;
      f32x2 xl0[4], xl1v[4], xl2v[4], xl3v[4];
      #pragma unroll
      for (int q = 0; q < 4; ++q) {
        xl0[q] = b2f2(v0[q]);
        xl1v[q] = b2f2(v1[q]);
        xl2v[q] = b2f2(v2[q]);
        xl3v[q] = b2f2(v3[q]);
      }
      f32x2 cv0 = {0.f, 0.f}, cv1 = {0.f, 0.f}, cv2 = {0.f, 0.f}, cv3 = {0.f, 0.f};
      #pragma unroll
      for (int q = 0; q < 4; ++q) {
        f32x2 t0 = xl0[q] + xr2[q];
        f32x2 t1 = xl1v[q] + xr2[q];
        f32x2 t2 = xl2v[q] + xr2[q];
        f32x2 t3 = xl3v[q] + xr2[q];
        f32x2 u0 = __builtin_elementwise_fma(c15, xl0[q],  __builtin_elementwise_abs(t0));
        f32x2 u1 = __builtin_elementwise_fma(c15, xl1v[q], __builtin_elementwise_abs(t1));
        f32x2 u2 = __builtin_elementwise_fma(c15, xl2v[q], __builtin_elementwise_abs(t2));
        f32x2 u3 = __builtin_elementwise_fma(c15, xl3v[q], __builtin_elementwise_abs(t3));
        cv0 = __builtin_elementwise_fma(att2[q], u0, cv0);
        cv1 = __builtin_elementwise_fma(att2[q], u1, cv1);
        cv2 = __builtin_elementwise_fma(att2[q], u2, cv2);
        cv3 = __builtin_elementwise_fma(att2[q], u3, cv3);
      }
      float c0 = cv0[0] + cv0[1];
      float c1 = cv1[0] + cv1[1];
      float c2 = cv2[0] + cv2[1];
      float c3 = cv3[0] + cv3[1];
      c0 += __shfl_xor(c0, 1, 64); c1 += __shfl_xor(c1, 1, 64);
      c2 += __shfl_xor(c2, 1, 64); c3 += __shfl_xor(c3, 1, 64);
      c0 += __shfl_xor(c0, 2, 64); c1 += __shfl_xor(c1, 2, 64);
      c2 += __shfl_xor(c2, 2, 64); c3 += __shfl_xor(c3, 2, 64);
      c0 += __shfl_xor(c0, 4, 64); c1 += __shfl_xor(c1, 4, 64);
      c2 += __shfl_xor(c2, 4, 64); c3 += __shfl_xor(c3, 4, 64);
      float l0 = c0 + dp;
      float l1 = c1 + dp;
      float l2 = c2 + dp;
      float l3 = c3 + dp;
      float pv0 = __expf(fminf(fmaxf(l0, -30.f), 30.f));
      float pv1 = __expf(fminf(fmaxf(l1, -30.f), 30.f)) * m1;
      float pv2 = __expf(fminf(fmaxf(l2, -30.f), 30.f)) * m2;
      float pv3 = __expf(fminf(fmaxf(l3, -30.f), 30.f)) * m3;
      s += (pv0 + pv1) + (pv2 + pv3);
      f32x2 pw0 = {pv0, pv0}, pw1 = {pv1, pv1}, pw2 = {pv2, pv2}, pw3 = {pv3, pv3};
      #pragma unroll
      for (int q = 0; q < 4; ++q) {
        f32x2 a = __builtin_elementwise_fma(pw0, xl0[q], accv[q]);
        a = __builtin_elementwise_fma(pw1, xl1v[q], a);
        a = __builtin_elementwise_fma(pw2, xl2v[q], a);
        accv[q] = __builtin_elementwise_fma(pw3, xl3v[q], a);
      }
    }
    float r = 1.f / s;
    u32x4 o;
    #pragma unroll
    for (int q = 0; q < 4; ++q) {
      u32 lo = f2b(fmaxf(fmaf(accv[q][0], r, params[512 + lane * 8 + 2 * q]),     0.f));
      u32 hi = f2b(fmaxf(fmaf(accv[q][1], r, params[512 + lane * 8 + 2 * q + 1]), 0.f));
      o[q] = lo | (hi << 16);
    }
    *(u32x4*)&hb[(size_t)i * 512 + lane * 8] = o;
  }
}

// ---------------- Layers 2+3 fused: one wave per node, 8 edge-slots x 8 channel-groups ----
// lane = e*8+g: slot e handles edges e0+e, e0+e+8, ...; group g handles L2 channels
// [5g,5g+5); g==0 additionally handles both L3 channels in-lane (no shfl).
// Logit reduce = 3 shfl per 8 edges; final cross-slot reduce once per node.
// xlp/xrp rows are 192B cacheline-aligned: per-edge gather = exactly 3 lines.
__global__ __launch_bounds__(256) void k_layer23f(const float* __restrict__ xlp, const float* __restrict__ xrp,
                                                  const int* __restrict__ row_ptr, const int* __restrict__ csr_src,
                                                  const float* __restrict__ params,
                                                  const int* __restrict__ flags, void* __restrict__ out) {
  int wid = blockIdx.x * 4 + (threadIdx.x >> 6);
  int lane = threadIdx.x & 63;
  int nw = gridDim.x * 4;
  int e = lane >> 3;   // edge slot 0..7
  int g = lane & 7;    // channel group 0..7
  int c0 = g * 5;      // L2 channels c0..c0+4
  float att2[5];
  #pragma unroll
  for (int u = 0; u < 5; ++u) att2[u] = params[1024 + c0 + u];
  float att3a = params[1104], att3b = params[1105];
  int isbf = flags[0];
  for (int i = wid; i < NN; i += nw) {
    int e0 = row_ptr[i], e1 = row_ptr[i + 1];
    const float* xri = &xrp[(size_t)i * 48];
    float xr2[5];
    #pragma unroll
    for (int u = 0; u < 5; ++u) xr2[u] = xri[c0 + u];
    float xr3a = xri[40], xr3b = xri[41];   // used by g==0 only
    float s2 = 0.f, s3 = 0.f;
    float acc2[5] = {0.f, 0.f, 0.f, 0.f, 0.f};
    float acc3a = 0.f, acc3b = 0.f;
    int nit = (e1 - e0 + 7) >> 3;
    for (int it = 0; it < nit; ++it) {
      int p = e0 + it * 8 + e;
      bool valid = p < e1;
      int j = csr_src[valid ? p : e1 - 1];
      const float* xlj = &xlp[(size_t)j * 48];
      float xl2[5];
      #pragma unroll
      for (int u = 0; u < 5; ++u) xl2[u] = xlj[c0 + u];
      float part = 0.f;
      #pragma unroll
      for (int u = 0; u < 5; ++u) {
        float t = xl2[u] + xr2[u];
        part = fmaf(att2[u], fmaxf(t, 0.2f * t), part);
      }
      part += __shfl_xor(part, 1, 64);
      part += __shfl_xor(part, 2, 64);
      part += __shfl_xor(part, 4, 64);
      float pv2 = valid ? __expf(fminf(fmaxf(part, -30.f), 30.f)) : 0.f;
      s2 += pv2;
      #pragma unroll
      for (int u = 0; u < 5; ++u) acc2[u] = fmaf(pv2, xl2[u], acc2[u]);
      if (g == 0) {   // layer3: 2 channels, fully in-lane
        float xl3a = xlj[40], xl3b = xlj[41];
        float ta = xl3a + xr3a, tb = xl3b + xr3b;
        float l3 = fmaf(att3a, fmaxf(ta, 0.2f * ta), att3b * fmaxf(tb, 0.2f * tb));
        float pv3 = valid ? __expf(fminf(fmaxf(l3, -30.f), 30.f)) : 0.f;
        s3 += pv3;
        acc3a = fmaf(pv3, xl3a, acc3a);
        acc3b = fmaf(pv3, xl3b, acc3b);
      }
    }
    // reduce across the 8 edge slots (lane bits 3..5)
    #pragma unroll
    for (int m = 8; m <= 32; m <<= 1) {
      #pragma unroll
      for (int u = 0; u < 5; ++u) acc2[u] += __shfl_xor(acc2[u], m, 64);
      s2 += __shfl_xor(s2, m, 64);
      acc3a += __shfl_xor(acc3a, m, 64);
      acc3b += __shfl_xor(acc3b, m, 64);
      s3 += __shfl_xor(s3, m, 64);
    }
    if (e == 0) {
      float r2 = 1.f / s2;
      #pragma unroll
      for (int u = 0; u < 5; ++u) {
        float v = acc2[u] * r2 + params[1064 + c0 + u];
        size_t o = (size_t)i * 40 + c0 + u;
        if (isbf) ((u16*)out)[o] = f2b(v); else ((float*)out)[o] = v;
      }
      if (g == 0) {
        float r3 = 1.f / s3;
        float va = acc3a * r3 + params[1106];
        float vb = acc3b * r3 + params[1107];
        size_t o = 2000000 + (size_t)i * 2;
        if (isbf) { ((u16*)out)[o] = f2b(va); ((u16*)out)[o + 1] = f2b(vb); }
        else      { ((float*)out)[o] = va;    ((float*)out)[o + 1] = vb; }
      }
    }
  }
}

extern "C" void kernel_launch(void* const* d_in, const int* in_sizes, int n_in,
                              void* d_out, int out_size, void* d_ws, size_t ws_size,
                              hipStream_t stream) {
  const void* x    = d_in[0];
  const int*  ei   = (const int*)d_in[1];
  const void* Wl1  = d_in[2];
  const void* Wr1  = d_in[3];
  const void* att1 = d_in[4];
  const void* b1   = d_in[5];
  const void* Wl2  = d_in[6];
  const void* Wr2  = d_in[7];
  const void* att2 = d_in[8];
  const void* b2   = d_in[9];
  const void* Wl3  = d_in[10];
  const void* Wr3  = d_in[11];
  const void* att3 = d_in[12];
  const void* b3   = d_in[13];
  (void)in_sizes; (void)n_in; (void)out_size;

  char* ws = (char*)d_ws;
  size_t off = 0;
  auto alloc = [&](size_t bytes) -> void* {
    void* p = ws + off;
    off = (off + bytes + 255) & ~(size_t)255;
    return p;
  };
  int*   flags   = (int*)  alloc(64);
  u16*   xb      = (u16*)  alloc((size_t)NN * 512 * 2);    // 51.2 MB (f32 fallback path)
  u16*   w1t     = (u16*)  alloc((size_t)1024 * 512 * 2);  // 1 MB
  u16*   xl1     = (u16*)  alloc((size_t)NN * 512 * 2);    // 51.2 MB
  u16*   xr1     = (u16*)  alloc((size_t)NN * 512 * 2);    // 51.2 MB
  u16*   hb      = (u16*)  alloc((size_t)NN * 512 * 2);    // 51.2 MB
  u16*   w23t    = (u16*)  alloc((size_t)96 * 512 * 2);
  float* xlp     = (float*)alloc((size_t)NN * 48 * 4);     // 9.6 MB (xl2|xl3, 192B rows)
  float* xrp     = (float*)alloc((size_t)NN * 48 * 4);     // 9.6 MB (xr2|xr3)
  float* params  = (float*)alloc(1108 * 4);
  int*   row_ptr = (int*)  alloc((NN + 1) * 4);
  int*   deg     = (int*)  alloc(NN * 4);
  int*   cursor  = (int*)  alloc(NN * 4);
  int*   csr_src = (int*)  alloc((NT + 16) * 4);
  int*   bsum    = (int*)  alloc(256 * 4);
  if (ws_size < off) return;  // ~228 MB needed

  hipLaunchKernelGGL(k_detect, dim3(1), dim3(128), 0, stream, x, (const void*)ei, flags);
  hipLaunchKernelGGL(k_convert_x, dim3(12500), dim3(256), 0, stream, x, flags, xb);
  hipLaunchKernelGGL(k_pack, dim3(2245), dim3(256), 0, stream, Wl1, Wr1, Wl2, Wr2, Wl3, Wr3,
                     att1, b1, att2, b2, att3, b3, flags, w1t, w23t, params);
  hipMemsetAsync(deg, 0, NN * 4, stream);
  hipLaunchKernelGGL(k_hist, dim3((NE + 255) / 256), dim3(256), 0, stream, ei, flags, deg);
  hipLaunchKernelGGL(k_scanA, dim3(NBLK_SCAN), dim3(256), 0, stream, deg, row_ptr, bsum);
  hipLaunchKernelGGL(k_scanB, dim3(1), dim3(256), 0, stream, bsum, row_ptr);
  hipLaunchKernelGGL(k_scanC, dim3(NBLK_SCAN), dim3(256), 0, stream, bsum, row_ptr, cursor);
  hipLaunchKernelGGL(k_scatter, dim3((NT + 255) / 256), dim3(256), 0, stream, ei, flags, cursor, csr_src);
  hipLaunchKernelGGL(k_gemm1, dim3(3136), dim3(256), 0, stream, x, xb, w1t, flags, xl1, xr1);
  hipLaunchKernelGGL(k_layer1f, dim3(4096), dim3(256), 0, stream, xl1, xr1, row_ptr, csr_src, params, hb);
  hipLaunchKernelGGL(k_gemm2, dim3(391), dim3(256), 0, stream, hb, w23t, xlp, xrp);
  hipLaunchKernelGGL(k_layer23f, dim3(4096), dim3(256), 0, stream, xlp, xrp, row_ptr, csr_src, params, flags, d_out);
}

// Round 11
// 440.305 us; speedup vs baseline: 1.0359x; 1.0277x over previous
//
#include <hip/hip_runtime.h>
#include <math.h>

typedef unsigned short u16;
typedef unsigned int   u32;
typedef __attribute__((ext_vector_type(8))) short bf16x8;
typedef __attribute__((ext_vector_type(4))) float f32x4;
typedef __attribute__((ext_vector_type(4))) u32   u32x4;

__device__ __forceinline__ float b2f(u16 u) {
  union { u32 i; float f; } v; v.i = ((u32)u) << 16; return v.f;
}
__device__ __forceinline__ u16 f2b(float f) {
  union { u32 i; float f; } v; v.f = f;
  u32 r = v.i + 0x7FFFu + ((v.i >> 16) & 1u);
  return (u16)(r >> 16);
}
__device__ __forceinline__ float blo(u32 w) {
  union { u32 i; float f; } v; v.i = w << 16; return v.f;
}
__device__ __forceinline__ float bhi(u32 w) {
  union { u32 i; float f; } v; v.i = w & 0xFFFF0000u; return v.f;
}
// packed f32->bf16 RNE conversion: dst.lo = cvt(a), dst.hi = cvt(b)
__device__ __forceinline__ u32 cvtpk(float a, float b) {
  u32 r;
  asm("v_cvt_pk_bf16_f32 %0, %1, %2" : "=v"(r) : "v"(a), "v"(b));
  return r;
}
// async global->LDS, 16B per lane; dest is wave-uniform base + lane*16
__device__ __forceinline__ void ld_lds16(const u16* g, u16* l) {
  __builtin_amdgcn_global_load_lds((const __attribute__((address_space(1))) void*)g,
                                   (__attribute__((address_space(3))) void*)l, 16, 0, 0);
}

#define NN 50000
#define NE 400000
#define NT 450000   // NE + NN self loops
#define NBLK_SCAN 196  // ceil(50000/256)

// ---------------- dtype detection ----------------
__global__ void k_detect(const void* x, const void* ei, int* flags) {
  __shared__ int cnt[2];
  int t = threadIdx.x; // 128 threads
  if (t < 2) cnt[t] = 0;
  __syncthreads();
  u16 u = ((const u16*)x)[t];
  int e = (u >> 7) & 0xFF;
  if (u == 0 || (e >= 90 && e <= 134)) atomicAdd(&cnt[0], 1);
  if (t < 16) {
    if (((const int*)ei)[2 * t + 1] == 0) atomicAdd(&cnt[1], 1);
  }
  __syncthreads();
  if (t == 0) {
    flags[0] = (cnt[0] >= 110) ? 1 : 0;
    flags[1] = (cnt[1] >= 15) ? 1 : 0;
  }
}

__device__ __forceinline__ int eidx(const int* ei, int pos, int i64) {
  return i64 ? ei[2 * pos] : ei[pos];
}

// merged packing: blocks [0,2048) -> w1t (1024 rows x 512, transposed Wl1|Wr1),
// [2048,2240) -> w23t, [2240,2245) -> params.
__global__ void k_pack(const void* Wl1, const void* Wr1, const void* Wl2, const void* Wr2,
                       const void* Wl3, const void* Wr3, const void* att1, const void* b1,
                       const void* att2, const void* b2, const void* att3, const void* b3,
                       const int* flags, u16* w1t, u16* w23t, float* params) {
  int b = blockIdx.x;
  int isbf = flags[0];
  if (b < 2048) {
    int t = b * 256 + threadIdx.x;
    int r = t >> 9;          // B-row 0..1023
    int k = t & 511;
    const void* W = (r < 512) ? Wl1 : Wr1;
    int cc = r & 511;
    u16 v = isbf ? ((const u16*)W)[k * 512 + cc] : f2b(((const float*)W)[k * 512 + cc]);
    w1t[(size_t)r * 512 + k] = v;
  } else if (b < 2240) {
    int t = (b - 2048) * 256 + threadIdx.x;
    int k = t / 96;
    int c = t % 96;
    const void* W = nullptr; int idx = 0;
    if (c < 40)      { W = Wl2; idx = k * 40 + c; }
    else if (c < 42) { W = Wl3; idx = k * 2 + (c - 40); }
    else if (c < 82) { W = Wr2; idx = k * 40 + (c - 42); }
    else if (c < 84) { W = Wr3; idx = k * 2 + (c - 82); }
    u16 v = 0;
    if (W) v = isbf ? ((const u16*)W)[idx] : f2b(((const float*)W)[idx]);
    w23t[c * 512 + k] = v;
  } else {
    int t = (b - 2240) * 256 + threadIdx.x;
    if (t >= 1108) return;
    const void* src; int idx;
    if (t < 512)       { src = att1; idx = t; }
    else if (t < 1024) { src = b1;   idx = t - 512; }
    else if (t < 1064) { src = att2; idx = t - 1024; }
    else if (t < 1104) { src = b2;   idx = t - 1064; }
    else if (t < 1106) { src = att3; idx = t - 1104; }
    else               { src = b3;   idx = t - 1106; }
    params[t] = isbf ? b2f(((const u16*)src)[idx]) : ((const float*)src)[idx];
  }
}

// ---------------- CSR build ----------------
__global__ void k_hist(const int* ei, const int* flags, int* deg) {
  int e = blockIdx.x * 256 + threadIdx.x;
  if (e >= NE) return;
  int d = eidx(ei, NE + e, flags[1]);
  atomicAdd(&deg[d], 1);
}

__global__ void k_scanA(const int* deg, int* row_ptr, int* bsum) {
  __shared__ int sh[256];
  int b = blockIdx.x, t = threadIdx.x;
  int i = b * 256 + t;
  int val = (i < NN) ? deg[i] + 1 : 0;
  sh[t] = val;
  __syncthreads();
  #pragma unroll
  for (int off = 1; off < 256; off <<= 1) {
    int v = (t >= off) ? sh[t - off] : 0;
    __syncthreads();
    sh[t] += v;
    __syncthreads();
  }
  if (i < NN) row_ptr[i] = sh[t] - val;
  if (t == 255) bsum[b] = sh[255];
}

__global__ void k_scanB(int* bsum, int* row_ptr) {
  __shared__ int sh[256];
  int t = threadIdx.x;
  int val = (t < NBLK_SCAN) ? bsum[t] : 0;
  sh[t] = val;
  __syncthreads();
  #pragma unroll
  for (int off = 1; off < 256; off <<= 1) {
    int v = (t >= off) ? sh[t - off] : 0;
    __syncthreads();
    sh[t] += v;
    __syncthreads();
  }
  if (t < NBLK_SCAN) bsum[t] = sh[t] - val;
  if (t == 255) row_ptr[NN] = sh[255];
}

__global__ void k_scanC(const int* bsum, int* row_ptr, int* cursor) {
  int i = blockIdx.x * 256 + threadIdx.x;
  if (i < NN) {
    int v = row_ptr[i] + bsum[blockIdx.x];
    row_ptr[i] = v;
    cursor[i] = v;
  }
}

__global__ void k_scatter(const int* ei, const int* flags, int* cursor, int* csr_src) {
  int t = blockIdx.x * 256 + threadIdx.x;
  if (t >= NT) return;
  int i64 = flags[1];
  int s, d;
  if (t < NE) { s = eidx(ei, t, i64); d = eidx(ei, NE + t, i64); }
  else        { s = d = t - NE; }
  int pos = atomicAdd(&cursor[d], 1);
  csr_src[pos] = s;
}

// ---------------- GEMM1: xl1/xr1[50000,512] = A @ w1t^T ----------------
// BK=64; B staged via global_load_lds (R6 lesson: B direct gather -> 145us).
// A staging is dtype-dual: bf16 input -> global_load_lds fast path (XOR source
// swizzle); f32 input -> reg-staged (2x dwordx4 + v_cvt_pk_bf16_f32 + ds_write
// to the SAME swizzled slot). This fuses the former k_convert_x kernel (one
// full 102MB read + 51MB write + re-read eliminated).
// XCD-aware mapping: XCD x owns m-tiles x*49.., all 8 n-tiles back-to-back.
__global__ __launch_bounds__(256) void k_gemm1(const void* __restrict__ xraw, const u16* __restrict__ Bt,
                                               const int* __restrict__ flags,
                                               u16* __restrict__ XL, u16* __restrict__ XR) {
  __shared__ __align__(16) u16 As[128 * 64];
  __shared__ __align__(16) u16 Bs[128 * 64];
  const int id  = blockIdx.x;
  const int xcd = id & 7;
  const int lb  = id >> 3;
  const int mt  = xcd * 49 + (lb >> 3);
  const int nt  = lb & 7;
  if (mt >= 391) return;
  const int m0 = mt * 128;
  const int n0 = nt * 128;
  const int isbf = flags[0];
  const u16*   __restrict__ Ab = (const u16*)xraw;
  const float* __restrict__ Af = (const float*)xraw;
  const int t = threadIdx.x;
  const int wave = t >> 6;
  const int lane = t & 63;
  const int wm = (wave >> 1) * 64;
  const int wn = (wave & 1) * 64;
  const int fr = lane & 15;
  const int fk = lane >> 4;
  const int srow = lane >> 3;               // 0..7: row within 8-row staging group
  const int schk = (lane & 7) ^ srow;       // XOR-swizzled source chunk (16B units)
  f32x4 acc[4][4] = {};
  for (int k0 = 0; k0 < 512; k0 += 64) {
    #pragma unroll
    for (int q = 0; q < 4; ++q) {
      int rbase = wave * 32 + q * 8;        // wave stages rows [wave*32, wave*32+32)
      ld_lds16(&Bt[(size_t)(n0 + rbase + srow) * 512 + k0 + schk * 8], &Bs[rbase * 64]);
    }
    if (isbf) {
      #pragma unroll
      for (int q = 0; q < 4; ++q) {
        int rbase = wave * 32 + q * 8;
        int gm = m0 + rbase + srow;
        if (gm > NN - 1) gm = NN - 1;       // clamp: never read past input x
        ld_lds16(&Ab[(size_t)gm * 512 + k0 + schk * 8], &As[rbase * 64]);
      }
    } else {
      #pragma unroll
      for (int q = 0; q < 4; ++q) {
        int rbase = wave * 32 + q * 8;
        int gm = m0 + rbase + srow;
        if (gm > NN - 1) gm = NN - 1;
        const float* src = Af + (size_t)gm * 512 + k0 + schk * 8;
        f32x4 a0 = *(const f32x4*)src;
        f32x4 a1 = *(const f32x4*)(src + 4);
        u32x4 o;
        o[0] = cvtpk(a0[0], a0[1]);
        o[1] = cvtpk(a0[2], a0[3]);
        o[2] = cvtpk(a1[0], a1[1]);
        o[3] = cvtpk(a1[2], a1[3]);
        *(u32x4*)&As[rbase * 64 + lane * 8] = o;  // same swizzled slot as DMA path
      }
    }
    __syncthreads();
    #pragma unroll
    for (int h = 0; h < 2; ++h) {
      int s = h * 4 + fk;                   // k-chunk select 0..7
      bf16x8 af[4], bb[4];
      #pragma unroll
      for (int i = 0; i < 4; ++i) {
        int row = wm + i * 16 + fr;
        af[i] = *(const bf16x8*)&As[row * 64 + ((s ^ (row & 7)) * 8)];
      }
      #pragma unroll
      for (int j = 0; j < 4; ++j) {
        int row = wn + j * 16 + fr;
        bb[j] = *(const bf16x8*)&Bs[row * 64 + ((s ^ (row & 7)) * 8)];
      }
      #pragma unroll
      for (int i = 0; i < 4; ++i)
        #pragma unroll
        for (int j = 0; j < 4; ++j)
          acc[i][j] = __builtin_amdgcn_mfma_f32_16x16x32_bf16(af[i], bb[j], acc[i][j], 0, 0, 0);
    }
    __syncthreads();
  }
  // epilogue: cvt_pk pairs (j, j+1) -> one packed convert per 2 outputs
  #pragma unroll
  for (int i = 0; i < 4; ++i) {
    #pragma unroll
    for (int r = 0; r < 4; ++r) {
      int gm = m0 + wm + i * 16 + fk * 4 + r;  // C/D: row=(lane>>4)*4+reg, col=lane&15
      if (gm < NN) {
        #pragma unroll
        for (int jp = 0; jp < 2; ++jp) {
          u32 pk = cvtpk(acc[i][2 * jp][r], acc[i][2 * jp + 1][r]);
          int gn0 = n0 + wn + (2 * jp) * 16 + fr;
          u16 lo = (u16)pk, hi = (u16)(pk >> 16);
          if (gn0 < 512) {                   // block-uniform: whole tile in XL or XR
            XL[(size_t)gm * 512 + gn0] = lo;
            XL[(size_t)gm * 512 + gn0 + 16] = hi;
          } else {
            XR[(size_t)gm * 512 + gn0 - 512] = lo;
            XR[(size_t)gm * 512 + gn0 - 496] = hi;
          }
        }
      }
    }
  }
}

// ---------------- GEMM2: xlp/xrp[50000,48] = hb @ w23t^T, 128-row tiles ----------------
// R7-proven LDS-staged version. Split + aligned outputs: xlp = channels 0..41,
// xrp = channels 42..83, 48-f32 rows (192B = 3 cache lines exactly).
__global__ __launch_bounds__(256) void k_gemm2(const u16* __restrict__ A, const u16* __restrict__ Bt,
                                               float* __restrict__ xlp, float* __restrict__ xrp) {
  __shared__ __align__(16) short As[128][40];
  __shared__ __align__(16) short Bs[96][40];
  const int m0 = blockIdx.x * 128;
  const int t = threadIdx.x;
  const int wave = t >> 6;
  const int lane = t & 63;
  const int fr = lane & 15;
  const int fk = lane >> 4;
  const int wm = wave * 32;
  f32x4 acc[2][6] = {};
  for (int k0 = 0; k0 < 512; k0 += 32) {
    #pragma unroll
    for (int h = 0; h < 2; ++h) {
      int c = t + h * 256;
      int row = c >> 2, kc = (c & 3) * 8;
      int gm = m0 + row;
      u32x4 va = {0, 0, 0, 0};
      if (gm < NN) va = *(const u32x4*)&A[(size_t)gm * 512 + k0 + kc];
      *(u32x4*)&As[row][kc] = va;
    }
    for (int c = t; c < 384; c += 256) {
      int row = c >> 2, kc = (c & 3) * 8;
      *(u32x4*)&Bs[row][kc] = *(const u32x4*)&Bt[row * 512 + k0 + kc];
    }
    __syncthreads();
    bf16x8 af[2], bb[6];
    #pragma unroll
    for (int i = 0; i < 2; ++i) af[i] = *(const bf16x8*)&As[wm + i * 16 + fr][fk * 8];
    #pragma unroll
    for (int j = 0; j < 6; ++j) bb[j] = *(const bf16x8*)&Bs[j * 16 + fr][fk * 8];
    #pragma unroll
    for (int i = 0; i < 2; ++i)
      #pragma unroll
      for (int j = 0; j < 6; ++j)
        acc[i][j] = __builtin_amdgcn_mfma_f32_16x16x32_bf16(af[i], bb[j], acc[i][j], 0, 0, 0);
    __syncthreads();
  }
  #pragma unroll
  for (int i = 0; i < 2; ++i) {
    #pragma unroll
    for (int j = 0; j < 6; ++j) {
      int gn = j * 16 + fr;
      if (gn < 84) {
        #pragma unroll
        for (int r = 0; r < 4; ++r) {
          int gm = m0 + wm + i * 16 + fk * 4 + r;
          if (gm < NN) {
            if (gn < 42) xlp[(size_t)gm * 48 + gn] = acc[i][j][r];
            else         xrp[(size_t)gm * 48 + gn - 42] = acc[i][j][r];
          }
        }
      }
    }
  }
}

// ---------------- Layer 1 fused: one wave per node, 4 edges in flight + index prefetch ----
// lrelu decomposition, fully in-register (R7-proven scalar form):
//   logit = sum_c 0.4*att_c*(|xl+xr| + 1.5*xl) + dR_i,  dR_i = sum_c 0.4*att_c*1.5*xr
__global__ __launch_bounds__(256) void k_layer1f(const u16* __restrict__ xl1, const u16* __restrict__ xr1,
                                                 const int* __restrict__ row_ptr, const int* __restrict__ csr_src,
                                                 const float* __restrict__ params, u16* __restrict__ hb) {
  int wid = blockIdx.x * 4 + (threadIdx.x >> 6);
  int lane = threadIdx.x & 63;
  int nw = gridDim.x * 4;
  float att4[8];
  #pragma unroll
  for (int k = 0; k < 8; ++k) att4[k] = 0.4f * params[lane * 8 + k];
  for (int i = wid; i < NN; i += nw) {
    int e0 = row_ptr[i], e1 = row_ptr[i + 1];
    u32x4 xrv = *(const u32x4*)&xr1[(size_t)i * 512 + lane * 8];
    float xr[8];
    #pragma unroll
    for (int q = 0; q < 4; ++q) { xr[2 * q] = blo(xrv[q]); xr[2 * q + 1] = bhi(xrv[q]); }
    // dR_i: per-node linear term over this head's 64 channels
    float dp = 0.f;
    #pragma unroll
    for (int k = 0; k < 8; ++k) dp = fmaf(att4[k], 1.5f * xr[k], dp);
    dp += __shfl_xor(dp, 1, 64);
    dp += __shfl_xor(dp, 2, 64);
    dp += __shfl_xor(dp, 4, 64);
    float s = 0.f;
    float acc[8] = {0.f, 0.f, 0.f, 0.f, 0.f, 0.f, 0.f, 0.f};
    // index prefetch: indices for iteration p are loaded during iteration p-4
    int q0 = csr_src[e0];
    int q1 = csr_src[e0 + 1 < e1 ? e0 + 1 : e1 - 1];
    int q2 = csr_src[e0 + 2 < e1 ? e0 + 2 : e1 - 1];
    int q3 = csr_src[e0 + 3 < e1 ? e0 + 3 : e1 - 1];
    for (int p = e0; p < e1; p += 4) {
      int j0 = q0, j1 = q1, j2 = q2, j3 = q3;
      u32x4 v0 = *(const u32x4*)&xl1[(size_t)j0 * 512 + lane * 8];
      u32x4 v1 = *(const u32x4*)&xl1[(size_t)j1 * 512 + lane * 8];
      u32x4 v2 = *(const u32x4*)&xl1[(size_t)j2 * 512 + lane * 8];
      u32x4 v3 = *(const u32x4*)&xl1[(size_t)j3 * 512 + lane * 8];
      int np = p + 4;
      if (np < e1) {
        q0 = csr_src[np];
        q1 = csr_src[np + 1 < e1 ? np + 1 : e1 - 1];
        q2 = csr_src[np + 2 < e1 ? np + 2 : e1 - 1];
        q3 = csr_src[np + 3 < e1 ? np + 3 : e1 - 1];
      }
      float m1 = (p + 1 < e1) ? 1.f : 0.f;
      float m2 = (p + 2 < e1) ? 1.f : 0.f;
      float m3 = (p + 3 < e1) ? 1.f : 0.f;
      float c0 = 0.f, c1 = 0.f, c2 = 0.f, c3 = 0.f;
      float xlv0[8], xlv1[8], xlv2[8], xlv3[8];
      #pragma unroll
      for (int q = 0; q < 4; ++q) {
        xlv0[2 * q] = blo(v0[q]); xlv0[2 * q + 1] = bhi(v0[q]);
        xlv1[2 * q] = blo(v1[q]); xlv1[2 * q + 1] = bhi(v1[q]);
        xlv2[2 * q] = blo(v2[q]); xlv2[2 * q + 1] = bhi(v2[q]);
        xlv3[2 * q] = blo(v3[q]); xlv3[2 * q + 1] = bhi(v3[q]);
      }
      #pragma unroll
      for (int k = 0; k < 8; ++k) {
        float t0 = xlv0[k] + xr[k];
        float t1 = xlv1[k] + xr[k];
        float t2 = xlv2[k] + xr[k];
        float t3 = xlv3[k] + xr[k];
        float u0 = fmaf(1.5f, xlv0[k], fabsf(t0));
        float u1 = fmaf(1.5f, xlv1[k], fabsf(t1));
        float u2 = fmaf(1.5f, xlv2[k], fabsf(t2));
        float u3 = fmaf(1.5f, xlv3[k], fabsf(t3));
        c0 = fmaf(att4[k], u0, c0);
        c1 = fmaf(att4[k], u1, c1);
        c2 = fmaf(att4[k], u2, c2);
        c3 = fmaf(att4[k], u3, c3);
      }
      c0 += __shfl_xor(c0, 1, 64); c1 += __shfl_xor(c1, 1, 64);
      c2 += __shfl_xor(c2, 1, 64); c3 += __shfl_xor(c3, 1, 64);
      c0 += __shfl_xor(c0, 2, 64); c1 += __shfl_xor(c1, 2, 64);
      c2 += __shfl_xor(c2, 2, 64); c3 += __shfl_xor(c3, 2, 64);
      c0 += __shfl_xor(c0, 4, 64); c1 += __shfl_xor(c1, 4, 64);
      c2 += __shfl_xor(c2, 4, 64); c3 += __shfl_xor(c3, 4, 64);
      float l0 = c0 + dp;
      float l1 = c1 + dp;
      float l2 = c2 + dp;
      float l3 = c3 + dp;
      float pv0 = __expf(fminf(fmaxf(l0, -30.f), 30.f));
      float pv1 = __expf(fminf(fmaxf(l1, -30.f), 30.f)) * m1;
      float pv2 = __expf(fminf(fmaxf(l2, -30.f), 30.f)) * m2;
      float pv3 = __expf(fminf(fmaxf(l3, -30.f), 30.f)) * m3;
      s += (pv0 + pv1) + (pv2 + pv3);
      #pragma unroll
      for (int k = 0; k < 8; ++k) {
        float a = fmaf(pv0, xlv0[k], acc[k]);
        a = fmaf(pv1, xlv1[k], a);
        a = fmaf(pv2, xlv2[k], a);
        acc[k] = fmaf(pv3, xlv3[k], a);
      }
    }
    float r = 1.f / s;
    u32x4 o;
    #pragma unroll
    for (int q = 0; q < 4; ++q) {
      u32 lo = f2b(fmaxf(fmaf(acc[2 * q],     r, params[512 + lane * 8 + 2 * q]),     0.f));
      u32 hi = f2b(fmaxf(fmaf(acc[2 * q + 1], r, params[512 + lane * 8 + 2 * q + 1]), 0.f));
      o[q] = lo | (hi << 16);
    }
    *(u32x4*)&hb[(size_t)i * 512 + lane * 8] = o;
  }
}

// ---------------- Layers 2+3 fused: one wave per node, 8 edge-slots x 8 channel-groups ----
// lane = e*8+g: slot e handles edges e0+e, e0+e+8, ...; group g handles L2 channels
// [5g,5g+5); g==0 additionally handles both L3 channels in-lane (no shfl).
// Logit reduce = 3 shfl per 8 edges; final cross-slot reduce once per node.
// xlp/xrp rows are 192B cacheline-aligned: per-edge gather = exactly 3 lines.
__global__ __launch_bounds__(256) void k_layer23f(const float* __restrict__ xlp, const float* __restrict__ xrp,
                                                  const int* __restrict__ row_ptr, const int* __restrict__ csr_src,
                                                  const float* __restrict__ params,
                                                  const int* __restrict__ flags, void* __restrict__ out) {
  int wid = blockIdx.x * 4 + (threadIdx.x >> 6);
  int lane = threadIdx.x & 63;
  int nw = gridDim.x * 4;
  int e = lane >> 3;   // edge slot 0..7
  int g = lane & 7;    // channel group 0..7
  int c0 = g * 5;      // L2 channels c0..c0+4
  float att2[5];
  #pragma unroll
  for (int u = 0; u < 5; ++u) att2[u] = params[1024 + c0 + u];
  float att3a = params[1104], att3b = params[1105];
  int isbf = flags[0];
  for (int i = wid; i < NN; i += nw) {
    int e0 = row_ptr[i], e1 = row_ptr[i + 1];
    const float* xri = &xrp[(size_t)i * 48];
    float xr2[5];
    #pragma unroll
    for (int u = 0; u < 5; ++u) xr2[u] = xri[c0 + u];
    float xr3a = xri[40], xr3b = xri[41];   // used by g==0 only
    float s2 = 0.f, s3 = 0.f;
    float acc2[5] = {0.f, 0.f, 0.f, 0.f, 0.f};
    float acc3a = 0.f, acc3b = 0.f;
    int nit = (e1 - e0 + 7) >> 3;
    for (int it = 0; it < nit; ++it) {
      int p = e0 + it * 8 + e;
      bool valid = p < e1;
      int j = csr_src[valid ? p : e1 - 1];
      const float* xlj = &xlp[(size_t)j * 48];
      float xl2[5];
      #pragma unroll
      for (int u = 0; u < 5; ++u) xl2[u] = xlj[c0 + u];
      float part = 0.f;
      #pragma unroll
      for (int u = 0; u < 5; ++u) {
        float t = xl2[u] + xr2[u];
        part = fmaf(att2[u], fmaxf(t, 0.2f * t), part);
      }
      part += __shfl_xor(part, 1, 64);
      part += __shfl_xor(part, 2, 64);
      part += __shfl_xor(part, 4, 64);
      float pv2 = valid ? __expf(fminf(fmaxf(part, -30.f), 30.f)) : 0.f;
      s2 += pv2;
      #pragma unroll
      for (int u = 0; u < 5; ++u) acc2[u] = fmaf(pv2, xl2[u], acc2[u]);
      if (g == 0) {   // layer3: 2 channels, fully in-lane
        float xl3a = xlj[40], xl3b = xlj[41];
        float ta = xl3a + xr3a, tb = xl3b + xr3b;
        float l3 = fmaf(att3a, fmaxf(ta, 0.2f * ta), att3b * fmaxf(tb, 0.2f * tb));
        float pv3 = valid ? __expf(fminf(fmaxf(l3, -30.f), 30.f)) : 0.f;
        s3 += pv3;
        acc3a = fmaf(pv3, xl3a, acc3a);
        acc3b = fmaf(pv3, xl3b, acc3b);
      }
    }
    // reduce across the 8 edge slots (lane bits 3..5)
    #pragma unroll
    for (int m = 8; m <= 32; m <<= 1) {
      #pragma unroll
      for (int u = 0; u < 5; ++u) acc2[u] += __shfl_xor(acc2[u], m, 64);
      s2 += __shfl_xor(s2, m, 64);
      acc3a += __shfl_xor(acc3a, m, 64);
      acc3b += __shfl_xor(acc3b, m, 64);
      s3 += __shfl_xor(s3, m, 64);
    }
    if (e == 0) {
      float r2 = 1.f / s2;
      #pragma unroll
      for (int u = 0; u < 5; ++u) {
        float v = acc2[u] * r2 + params[1064 + c0 + u];
        size_t o = (size_t)i * 40 + c0 + u;
        if (isbf) ((u16*)out)[o] = f2b(v); else ((float*)out)[o] = v;
      }
      if (g == 0) {
        float r3 = 1.f / s3;
        float va = acc3a * r3 + params[1106];
        float vb = acc3b * r3 + params[1107];
        size_t o = 2000000 + (size_t)i * 2;
        if (isbf) { ((u16*)out)[o] = f2b(va); ((u16*)out)[o + 1] = f2b(vb); }
        else      { ((float*)out)[o] = va;    ((float*)out)[o + 1] = vb; }
      }
    }
  }
}

extern "C" void kernel_launch(void* const* d_in, const int* in_sizes, int n_in,
                              void* d_out, int out_size, void* d_ws, size_t ws_size,
                              hipStream_t stream) {
  const void* x    = d_in[0];
  const int*  ei   = (const int*)d_in[1];
  const void* Wl1  = d_in[2];
  const void* Wr1  = d_in[3];
  const void* att1 = d_in[4];
  const void* b1   = d_in[5];
  const void* Wl2  = d_in[6];
  const void* Wr2  = d_in[7];
  const void* att2 = d_in[8];
  const void* b2   = d_in[9];
  const void* Wl3  = d_in[10];
  const void* Wr3  = d_in[11];
  const void* att3 = d_in[12];
  const void* b3   = d_in[13];
  (void)in_sizes; (void)n_in; (void)out_size;

  char* ws = (char*)d_ws;
  size_t off = 0;
  auto alloc = [&](size_t bytes) -> void* {
    void* p = ws + off;
    off = (off + bytes + 255) & ~(size_t)255;
    return p;
  };
  int*   flags   = (int*)  alloc(64);
  u16*   w1t     = (u16*)  alloc((size_t)1024 * 512 * 2);  // 1 MB
  u16*   xl1     = (u16*)  alloc((size_t)NN * 512 * 2);    // 51.2 MB
  u16*   xr1     = (u16*)  alloc((size_t)NN * 512 * 2);    // 51.2 MB
  u16*   hb      = (u16*)  alloc((size_t)NN * 512 * 2);    // 51.2 MB
  u16*   w23t    = (u16*)  alloc((size_t)96 * 512 * 2);
  float* xlp     = (float*)alloc((size_t)NN * 48 * 4);     // 9.6 MB (xl2|xl3, 192B rows)
  float* xrp     = (float*)alloc((size_t)NN * 48 * 4);     // 9.6 MB (xr2|xr3)
  float* params  = (float*)alloc(1108 * 4);
  int*   row_ptr = (int*)  alloc((NN + 1) * 4);
  int*   deg     = (int*)  alloc(NN * 4);
  int*   cursor  = (int*)  alloc(NN * 4);
  int*   csr_src = (int*)  alloc((NT + 16) * 4);
  int*   bsum    = (int*)  alloc(256 * 4);
  if (ws_size < off) return;  // ~177 MB needed

  hipLaunchKernelGGL(k_detect, dim3(1), dim3(128), 0, stream, x, (const void*)ei, flags);
  hipLaunchKernelGGL(k_pack, dim3(2245), dim3(256), 0, stream, Wl1, Wr1, Wl2, Wr2, Wl3, Wr3,
                     att1, b1, att2, b2, att3, b3, flags, w1t, w23t, params);
  hipMemsetAsync(deg, 0, NN * 4, stream);
  hipLaunchKernelGGL(k_hist, dim3((NE + 255) / 256), dim3(256), 0, stream, ei, flags, deg);
  hipLaunchKernelGGL(k_scanA, dim3(NBLK_SCAN), dim3(256), 0, stream, deg, row_ptr, bsum);
  hipLaunchKernelGGL(k_scanB, dim3(1), dim3(256), 0, stream, bsum, row_ptr);
  hipLaunchKernelGGL(k_scanC, dim3(NBLK_SCAN), dim3(256), 0, stream, bsum, row_ptr, cursor);
  hipLaunchKernelGGL(k_scatter, dim3((NT + 255) / 256), dim3(256), 0, stream, ei, flags, cursor, csr_src);
  hipLaunchKernelGGL(k_gemm1, dim3(3136), dim3(256), 0, stream, x, w1t, flags, xl1, xr1);
  hipLaunchKernelGGL(k_layer1f, dim3(4096), dim3(256), 0, stream, xl1, xr1, row_ptr, csr_src, params, hb);
  hipLaunchKernelGGL(k_gemm2, dim3(391), dim3(256), 0, stream, hb, w23t, xlp, xrp);
  hipLaunchKernelGGL(k_layer23f, dim3(4096), dim3(256), 0, stream, xlp, xrp, row_ptr, csr_src, params, flags, d_out);
}